// Round 13
// baseline (157.705 us; speedup 1.0000x reference)
//
#include <hip/hip_runtime.h>

typedef __bf16 bf16;
typedef __bf16 bf16x4 __attribute__((ext_vector_type(4)));
typedef __bf16 bf16x8 __attribute__((ext_vector_type(8)));
typedef float f32x4 __attribute__((ext_vector_type(4)));

#define DEV static __device__ __forceinline__

constexpr int S  = 2048;
constexpr int D  = 2048;
constexpr int H  = 32;
constexpr int G  = 8;
constexpr int HD = 64;
constexpr int NQG = 2 * H * HD;  // 4096
constexpr int LDP = 136;         // padded LDS stride for attn P tile (128+8)

DEV bf16x8 load8(const bf16* p) { return *reinterpret_cast<const bf16x8*>(p); }

DEV f32x4 mfma16(bf16x8 a, bf16x8 b, f32x4 c) {
  return __builtin_amdgcn_mfma_f32_16x16x32_bf16(a, b, c, 0, 0, 0);
}

DEV void gload_lds16(const bf16* g, bf16* l) {
  __builtin_amdgcn_global_load_lds(
      (const __attribute__((address_space(1))) void*)g,
      (__attribute__((address_space(3))) void*)l, 16, 0, 0);
}

// Raw barrier / counted waitcnt. __syncthreads drains vmcnt(0) and defeats
// cross-barrier prefetch. GEMMs use prefetch DISTANCE 2 + vmcnt(8): loads
// for tile t+1 stay in flight across the whole of iter t (r10's distance-1
// + drain exposed ~500cy/step and regressed 40%).
#define BARRIER()  asm volatile("s_barrier" ::: "memory")
#define VMDRAIN()  asm volatile("s_waitcnt vmcnt(0)" ::: "memory")
#define VMWAIT8()  asm volatile("s_waitcnt vmcnt(8)" ::: "memory")

// Stage a [ROWS][64] bf16 tile into LDS with chunk-XOR swizzle (4-wave form).
template <int NISS>  // ROWS = NISS*32 (4 -> 128 rows, 2 -> 64 rows)
DEV void stage_tile(bf16* lds, const bf16* src_row0, size_t ld, int k0, int tid) {
  const int w = tid >> 6, l = tid & 63;
#pragma unroll
  for (int i = 0; i < NISS; ++i) {
    int blk = w * NISS + i;            // 1KB LDS block
    int r = blk * 8 + (l >> 3);
    int c = (l & 7) ^ (r & 7);
    gload_lds16(src_row0 + (size_t)r * ld + k0 + c * 8, lds + blk * 512);
  }
}

// 8-wave form: one issue per wave stages a 64x64 tile (8 x 1KB blocks).
DEV void stage64_8w(bf16* lds, const bf16* src_row0, size_t ld, int k0, int tid) {
  const int w = tid >> 6, l = tid & 63;
  int r = w * 8 + (l >> 3);
  int c = (l & 7) ^ (r & 7);
  gload_lds16(src_row0 + (size_t)r * ld + k0 + c * 8, lds + w * 512);
}

// Read an 8-elem fragment (logical chunk) from a swizzled [*][64] LDS tile.
DEV bf16x8 fragr(const bf16* T, int row, int chunk) {
  return load8(T + row * 64 + (((chunk ^ (row & 7)) << 3)));
}

DEV float fexp2(float x) { return __builtin_amdgcn_exp2f(x); }
DEV float frcp(float x)  { return __builtin_amdgcn_rcpf(x); }

// ---------------------------------------------------------------------------
// f32 -> bf16 conversions for x, Wq, Wk, Wv (Wo rides inside gemm_qkv).
// ---------------------------------------------------------------------------
__global__ __launch_bounds__(256) void cvt_all(
    const float* __restrict__ x,  const float* __restrict__ wq,
    const float* __restrict__ wk, const float* __restrict__ wv,
    bf16* __restrict__ xb,  bf16* __restrict__ wqb, bf16* __restrict__ wkb,
    bf16* __restrict__ wvb)
{
  long c = (long)blockIdx.x * 256 + threadIdx.x;   // 8-elem chunk id
  const float* src; bf16* dst; long off;
  if      (c <  524288) { src = x;  dst = xb;  off = c; }
  else if (c < 1572864) { src = wq; dst = wqb; off = c -  524288; }
  else if (c < 1703936) { src = wk; dst = wkb; off = c - 1572864; }
  else                  { src = wv; dst = wvb; off = c - 1703936; }
  long i = off * 8;
  const float4* p = reinterpret_cast<const float4*>(src + i);
  float4 a = p[0], b = p[1];
  bf16x8 o;
  o[0] = (bf16)a.x; o[1] = (bf16)a.y; o[2] = (bf16)a.z; o[3] = (bf16)a.w;
  o[4] = (bf16)b.x; o[5] = (bf16)b.y; o[6] = (bf16)b.z; o[7] = (bf16)b.w;
  *reinterpret_cast<bf16x8*>(dst + i) = o;
}

// ---------------------------------------------------------------------------
// Fused RMSNorm + RoPE epilogue helper (wave owns one head's 64 channels).
// ---------------------------------------------------------------------------
DEV void rms_rope_store(f32x4 acc[4][4], bf16* __restrict__ dst,
                        const float* __restrict__ w,
                        const float* __restrict__ cosb,
                        const float* __restrict__ sinb,
                        int s0, int ln, int hi, float outscale)
{
  float wgt[4];
#pragma unroll
  for (int ni = 0; ni < 4; ++ni) wgt[ni] = 1.0f + w[ni * 16 + ln];
#pragma unroll
  for (int mi = 0; mi < 4; ++mi)
#pragma unroll
    for (int j = 0; j < 4; ++j) {
      int s = s0 + mi * 16 + hi * 4 + j;
      float v0 = acc[mi][0][j], v1 = acc[mi][1][j];
      float v2 = acc[mi][2][j], v3 = acc[mi][3][j];
      float ss = v0 * v0 + v1 * v1 + v2 * v2 + v3 * v3;
      ss += __shfl_xor(ss, 1);
      ss += __shfl_xor(ss, 2);
      ss += __shfl_xor(ss, 4);
      ss += __shfl_xor(ss, 8);
      float inv = __builtin_amdgcn_rsqf(ss * (1.0f / 64.0f) + 1e-6f);
      float xf[4] = {v0 * inv * wgt[0], v1 * inv * wgt[1],
                     v2 * inv * wgt[2], v3 * inv * wgt[3]};
#pragma unroll
      for (int ni = 0; ni < 4; ++ni) {
        int d = ni * 16 + ln;
        float c  = cosb[s * HD + d];
        float sn = sinb[s * HD + d];
        float rot = (ni < 2) ? -xf[ni + 2] : xf[ni - 2];
        dst[(size_t)s * HD + d] = (bf16)((xf[ni] * c + rot * sn) * outscale);
      }
    }
}

// ---------------------------------------------------------------------------
// Fused QKV projection + RMSNorm + RoPE epilogue.
// 128x128 tile, BK=64, distance-2 double-buffered pipeline:
//   iter t: compute slot[t&1]; barrier; stage t+2 into slot[t&1];
//           vmcnt(8) (waits only t+1's loads, issued a FULL iter ago);
//           barrier.
// blockIdx.x 40..47 = ride-along Wo f32->bf16 conversion blocks.
// ---------------------------------------------------------------------------
__global__ __launch_bounds__(256, 2) void gemm_qkv(
    const bf16* __restrict__ X, const bf16* __restrict__ Wq,
    const bf16* __restrict__ Wk, const bf16* __restrict__ Wv,
    const float* __restrict__ cosb, const float* __restrict__ sinb,
    const float* __restrict__ qw, const float* __restrict__ kw,
    const float* __restrict__ wo, bf16* __restrict__ wob,
    bf16* __restrict__ qg, bf16* __restrict__ qrot,
    bf16* __restrict__ krot, bf16* __restrict__ vt)
{
  __shared__ __align__(16) bf16 As[2][128 * 64];
  __shared__ __align__(16) bf16 Bs[2][128 * 64];

  const int tid = threadIdx.x;
  const int nt  = blockIdx.x;

  if (nt >= 40) {
    // ride-along Wo conversion: 128 blocks x 256 thr x 16 iters x 8 elems
    long base = (long)((nt - 40) * 16 + blockIdx.y) * 256 + tid;
#pragma unroll
    for (int it = 0; it < 16; ++it) {
      long i = (base + (long)it * 32768) * 8;
      const float4* p = reinterpret_cast<const float4*>(wo + i);
      float4 a = p[0], b = p[1];
      bf16x8 o;
      o[0] = (bf16)a.x; o[1] = (bf16)a.y; o[2] = (bf16)a.z; o[3] = (bf16)a.w;
      o[4] = (bf16)b.x; o[5] = (bf16)b.y; o[6] = (bf16)b.z; o[7] = (bf16)b.w;
      *reinterpret_cast<bf16x8*>(wob + i) = o;
    }
    return;
  }

  const int wave = tid >> 6;
  const int lane = tid & 63;
  const int ln = lane & 15, hi = lane >> 4;
  const int wm = wave >> 1, wn = wave & 1;
  const int m0 = blockIdx.y * 128;

  const bf16* W; int n0;
  if (nt < 32)      { W = Wq; n0 = nt * 128; }
  else if (nt < 36) { W = Wk; n0 = (nt - 32) * 128; }
  else              { W = Wv; n0 = (nt - 36) * 128; }

  const bf16* arow = X + (size_t)m0 * D;
  const bf16* brow = W + (size_t)n0 * D;

  f32x4 acc[4][4] = {};

  // prologue: stage K-tiles 0 and 1; wait for tile 0 (8 loads of tile 1 stay)
  stage_tile<4>(As[0], arow, D, 0, tid);
  stage_tile<4>(Bs[0], brow, D, 0, tid);
  stage_tile<4>(As[1], arow, D, 64, tid);
  stage_tile<4>(Bs[1], brow, D, 64, tid);
  VMWAIT8();
  BARRIER();

  constexpr int NT = D / 64;  // 32
  for (int t = 0; t < NT; ++t) {
    const bf16* Asc = As[t & 1];
    const bf16* Bsc = Bs[t & 1];
#pragma unroll
    for (int kk = 0; kk < 64; kk += 32) {
      bf16x8 a[4], b[4];
#pragma unroll
      for (int mi = 0; mi < 4; ++mi) a[mi] = fragr(Asc, wm * 64 + mi * 16 + ln, (kk >> 3) + hi);
#pragma unroll
      for (int ni = 0; ni < 4; ++ni) b[ni] = fragr(Bsc, wn * 64 + ni * 16 + ln, (kk >> 3) + hi);
      __builtin_amdgcn_s_setprio(1);
#pragma unroll
      for (int mi = 0; mi < 4; ++mi)
#pragma unroll
        for (int ni = 0; ni < 4; ++ni)
          acc[mi][ni] = mfma16(a[mi], b[ni], acc[mi][ni]);
      __builtin_amdgcn_s_setprio(0);
    }
    BARRIER();                       // all waves done reading slot[t&1]
    if (t + 2 < NT) {
      stage_tile<4>(As[t & 1], arow, D, (t + 2) * 64, tid);
      stage_tile<4>(Bs[t & 1], brow, D, (t + 2) * 64, tid);
      VMWAIT8();                     // t+1's loads landed; t+2's 8 in flight
    } else if (t + 1 < NT) {
      VMDRAIN();                     // nothing staged: drain t+1's loads
    }
    BARRIER();                       // block-wide: slot[(t+1)&1] ready
  }

  const int s0 = m0 + wm * 64;
  if (nt < 32) {
    if (wn == 0) {
      rms_rope_store(acc, qrot + (size_t)nt * S * HD, qw, cosb, sinb,
                     s0, ln, hi, 0.18033688011111204f);
    } else {
#pragma unroll
      for (int mi = 0; mi < 4; ++mi)
#pragma unroll
        for (int ni = 0; ni < 4; ++ni)
#pragma unroll
          for (int j = 0; j < 4; ++j) {
            int r = s0 + mi * 16 + hi * 4 + j;
            int c = nt * 128 + 64 + ni * 16 + ln;
            qg[(size_t)r * NQG + c] = (bf16)acc[mi][ni][j];
          }
    }
  } else if (nt < 36) {
    int g8 = (nt - 32) * 2 + wn;
    rms_rope_store(acc, krot + (size_t)g8 * S * HD, kw, cosb, sinb,
                   s0, ln, hi, 1.0f);
  } else {
    int nrel = (nt - 36) * 128;
#pragma unroll
    for (int mi = 0; mi < 4; ++mi)
#pragma unroll
      for (int ni = 0; ni < 4; ++ni)
#pragma unroll
        for (int j = 0; j < 4; ++j) {
          int r = s0 + mi * 16 + hi * 4 + j;                    // s
          int c = nrel + wn * 64 + ni * 16 + ln;                // channel
          vt[(size_t)c * S + r] = (bf16)acc[mi][ni][j];
        }
  }
}

// ---------------------------------------------------------------------------
// Output projection, 128x128 tile, same distance-2 pipeline. Grid (16,16)
// = 256 blocks = exactly 1/CU. f32 output.
// ---------------------------------------------------------------------------
__global__ __launch_bounds__(256, 2) void gemm_out(
    const bf16* __restrict__ A, const bf16* __restrict__ W,
    float* __restrict__ C)
{
  __shared__ __align__(16) bf16 As[2][128 * 64];
  __shared__ __align__(16) bf16 Bs[2][128 * 64];

  const int tid  = threadIdx.x;
  const int wave = tid >> 6;
  const int lane = tid & 63;
  const int ln = lane & 15, hi = lane >> 4;
  const int wm = wave >> 1, wn = wave & 1;
  const int m0 = blockIdx.y * 128;
  const int n0 = blockIdx.x * 128;

  const bf16* arow = A + (size_t)m0 * D;
  const bf16* brow = W + (size_t)n0 * D;

  f32x4 acc[4][4] = {};

  stage_tile<4>(As[0], arow, D, 0, tid);
  stage_tile<4>(Bs[0], brow, D, 0, tid);
  stage_tile<4>(As[1], arow, D, 64, tid);
  stage_tile<4>(Bs[1], brow, D, 64, tid);
  VMWAIT8();
  BARRIER();

  constexpr int NT = D / 64;  // 32
  for (int t = 0; t < NT; ++t) {
    const bf16* Asc = As[t & 1];
    const bf16* Bsc = Bs[t & 1];
#pragma unroll
    for (int kk = 0; kk < 64; kk += 32) {
      bf16x8 a[4], b[4];
#pragma unroll
      for (int mi = 0; mi < 4; ++mi) a[mi] = fragr(Asc, wm * 64 + mi * 16 + ln, (kk >> 3) + hi);
#pragma unroll
      for (int ni = 0; ni < 4; ++ni) b[ni] = fragr(Bsc, wn * 64 + ni * 16 + ln, (kk >> 3) + hi);
      __builtin_amdgcn_s_setprio(1);
#pragma unroll
      for (int mi = 0; mi < 4; ++mi)
#pragma unroll
        for (int ni = 0; ni < 4; ++ni)
          acc[mi][ni] = mfma16(a[mi], b[ni], acc[mi][ni]);
      __builtin_amdgcn_s_setprio(0);
    }
    BARRIER();
    if (t + 2 < NT) {
      stage_tile<4>(As[t & 1], arow, D, (t + 2) * 64, tid);
      stage_tile<4>(Bs[t & 1], brow, D, (t + 2) * 64, tid);
      VMWAIT8();
    } else if (t + 1 < NT) {
      VMDRAIN();
    }
    BARRIER();
  }

#pragma unroll
  for (int mi = 0; mi < 4; ++mi)
#pragma unroll
    for (int ni = 0; ni < 4; ++ni)
#pragma unroll
      for (int j = 0; j < 4; ++j) {
        int r = m0 + wm * 64 + mi * 16 + hi * 4 + j;
        int c = n0 + wn * 64 + ni * 16 + ln;
        C[(size_t)r * D + c] = acc[mi][ni][j];
      }
}

// ---------------------------------------------------------------------------
// Flash attention (unchanged from round 12): swapped QK^T, 8 waves/block,
// 2 heads share K/V staging, KVBLK=128, raw-barrier dbuf prefetch.
// ---------------------------------------------------------------------------
DEV void attn_phase(const bf16* __restrict__ qrot, const bf16* __restrict__ krow,
                    const bf16* __restrict__ vrow, const bf16* __restrict__ qg,
                    bf16* __restrict__ ctxg,
                    bf16* Kbase, bf16* Vbase, bf16* pw,
                    int h, int qchunk, int ln, int hi, int tid)
{
  const int nt = (qchunk >> 1) + 1;   // 128-key rounds; last may be part-masked
  const int qb = qchunk * 64 + ((tid >> 6) & 3) * 16;
  const int q  = qb + ln;

  const bf16* qbase = qrot + ((size_t)h * S + qb + ln) * HD + hi * 8;
  bf16x8 q0 = load8(qbase);
  bf16x8 q1 = load8(qbase + 32);

  f32x4 po[4] = {};
  float m = -INFINITY, l = 0.f;

  stage64_8w(Kbase,        krow,            64, 0,  tid);
  stage64_8w(Kbase + 4096, krow + 64 * 64,  64, 0,  tid);
  stage64_8w(Vbase,        vrow,            S,  0,  tid);
  stage64_8w(Vbase + 4096, vrow,            S,  64, tid);
  VMDRAIN();
  BARRIER();

  int cur = 0;
  for (int t = 0; t < nt; ++t) {
    const bf16* Kc = Kbase + cur * 8192;
    const bf16* Vc = Vbase + cur * 8192;

    if (t + 1 < nt) {
      bf16* Kn = Kbase + (cur ^ 1) * 8192;
      bf16* Vn = Vbase + (cur ^ 1) * 8192;
      stage64_8w(Kn,        krow + (size_t)(t + 1) * 128 * 64,        64, 0, tid);
      stage64_8w(Kn + 4096, krow + ((size_t)(t + 1) * 128 + 64) * 64, 64, 0, tid);
      stage64_8w(Vn,        vrow, S, (t + 1) * 128,      tid);
      stage64_8w(Vn + 4096, vrow, S, (t + 1) * 128 + 64, tid);
    }

    f32x4 sc[2][4];
#pragma unroll
    for (int s = 0; s < 2; ++s) {
      const bf16* Ks = Kc + s * 4096;
      bf16x8 kf0[4], kf1[4];
#pragma unroll
      for (int kr = 0; kr < 4; ++kr) {
        kf0[kr] = fragr(Ks, kr * 16 + ln, hi);
        kf1[kr] = fragr(Ks, kr * 16 + ln, hi + 4);
      }
      __builtin_amdgcn_s_setprio(1);
#pragma unroll
      for (int kr = 0; kr < 4; ++kr) {
        f32x4 z = {};
        z = mfma16(kf0[kr], q0, z);
        sc[s][kr] = mfma16(kf1[kr], q1, z);
      }
      __builtin_amdgcn_s_setprio(0);
    }

    float pmax = -INFINITY;
    if (t == nt - 1) {
      const int key0 = t * 128;
#pragma unroll
      for (int s = 0; s < 2; ++s)
#pragma unroll
        for (int kr = 0; kr < 4; ++kr)
#pragma unroll
          for (int j = 0; j < 4; ++j) {
            int key = key0 + s * 64 + kr * 16 + hi * 4 + j;
            float v = (key <= q) ? sc[s][kr][j] : -INFINITY;
            sc[s][kr][j] = v;
            pmax = fmaxf(pmax, v);
          }
    } else {
#pragma unroll
      for (int s = 0; s < 2; ++s)
#pragma unroll
        for (int kr = 0; kr < 4; ++kr)
#pragma unroll
          for (int j = 0; j < 4; ++j) pmax = fmaxf(pmax, sc[s][kr][j]);
    }
    pmax = fmaxf(pmax, __shfl_xor(pmax, 16));
    pmax = fmaxf(pmax, __shfl_xor(pmax, 32));

    if (__any(pmax > m + 8.0f)) {
      float mn = fmaxf(m, pmax);
      float c  = fexp2(m - mn);
      l *= c;
      float cc[4];
#pragma unroll
      for (int j = 0; j < 4; ++j) cc[j] = __shfl(c, hi * 4 + j);
#pragma unroll
      for (int dt = 0; dt < 4; ++dt)
#pragma unroll
        for (int j = 0; j < 4; ++j) po[dt][j] *= cc[j];
      m = mn;
    }

    float ps = 0.f;
#pragma unroll
    for (int s = 0; s < 2; ++s)
#pragma unroll
      for (int kr = 0; kr < 4; ++kr)
#pragma unroll
        for (int j = 0; j < 4; ++j) {
          float e = fexp2(sc[s][kr][j] - m);
          sc[s][kr][j] = e;
          ps += e;
        }
    ps += __shfl_xor(ps, 16);
    ps += __shfl_xor(ps, 32);
    l += ps;

#pragma unroll
    for (int s = 0; s < 2; ++s)
#pragma unroll
      for (int kr = 0; kr < 4; ++kr) {
        unsigned w0, w1;
        asm("v_cvt_pk_bf16_f32 %0, %1, %2" : "=v"(w0) : "v"(sc[s][kr][0]), "v"(sc[s][kr][1]));
        asm("v_cvt_pk_bf16_f32 %0, %1, %2" : "=v"(w1) : "v"(sc[s][kr][2]), "v"(sc[s][kr][3]));
        uint2 w = {w0, w1};
        *reinterpret_cast<uint2*>(pw + ln * LDP + s * 64 + kr * 16 + hi * 4) = w;
      }
    bf16x8 pa[4];
#pragma unroll
    for (int sl = 0; sl < 4; ++sl) pa[sl] = load8(pw + ln * LDP + sl * 32 + hi * 8);

    __builtin_amdgcn_s_setprio(1);
#pragma unroll
    for (int sl = 0; sl < 4; ++sl) {
      const bf16* Vs = Vc + (sl >> 1) * 4096;
      const int ch = (sl & 1) * 4 + hi;
#pragma unroll
      for (int dt = 0; dt < 4; ++dt)
        po[dt] = mfma16(pa[sl], fragr(Vs, dt * 16 + ln, ch), po[dt]);
    }
    __builtin_amdgcn_s_setprio(0);

    VMDRAIN();
    BARRIER();
    cur ^= 1;
  }

  float lf[4];
#pragma unroll
  for (int j = 0; j < 4; ++j) lf[j] = __shfl(l, hi * 4 + j);
#pragma unroll
  for (int dt = 0; dt < 4; ++dt)
#pragma unroll
    for (int j = 0; j < 4; ++j) {
      int qq = qb + hi * 4 + j;
      int d  = dt * 16 + ln;
      float o  = po[dt][j] * frcp(lf[j]);
      float gv = (float)qg[(size_t)qq * NQG + h * 128 + 64 + d];
      float sg = frcp(1.0f + fexp2(gv * -1.442695040888963f));
      ctxg[(size_t)qq * D + h * 64 + d] = (bf16)(o * sg);
    }
}

__global__ __launch_bounds__(512) void attn(
    const bf16* __restrict__ qrot, const bf16* __restrict__ krot,
    const bf16* __restrict__ vt, const bf16* __restrict__ qg,
    bf16* __restrict__ ctxg)
{
  __shared__ __align__(16) bf16 Kbuf[2][2][64 * 64];   // [dbuf][sub]
  __shared__ __align__(16) bf16 Vbuf[2][2][64 * 64];
  __shared__ __align__(16) bf16 Pl[8][16 * LDP];

  const int tid  = threadIdx.x;
  const int lane = tid & 63;
  const int ln = lane & 15, hi = lane >> 4;

  const int bid = blockIdx.x;
  const int g   = bid & 7;             // XCD-aware: bid%8 shares KV group
  const int i   = bid >> 3;            // 0..31
  const int hp  = i & 1;
  const int pr  = i >> 1;              // 0..15
  const int h   = g * 4 + hp * 2 + ((tid >> 6) >> 2);  // per-wave head
  bf16* pw = &Pl[tid >> 6][0];

  const bf16* krow = krot + (size_t)g * S * HD;   // [key][d], ld=64
  const bf16* vrow = vt + (size_t)g * 64 * S;     // [channel][s], ld=S

  attn_phase(qrot, krow, vrow, qg, ctxg,
             &Kbuf[0][0][0], &Vbuf[0][0][0], pw, h, pr, ln, hi, tid);
  attn_phase(qrot, krow, vrow, qg, ctxg,
             &Kbuf[0][0][0], &Vbuf[0][0][0], pw, h, 31 - pr, ln, hi, tid);
}

// ---------------------------------------------------------------------------
extern "C" void kernel_launch(void* const* d_in, const int* in_sizes, int n_in,
                              void* d_out, int out_size, void* d_ws, size_t ws_size,
                              hipStream_t stream) {
  const float* x    = (const float*)d_in[0];
  const float* cosb = (const float*)d_in[2];
  const float* sinb = (const float*)d_in[3];
  const float* Wq   = (const float*)d_in[4];
  const float* Wk   = (const float*)d_in[5];
  const float* Wv   = (const float*)d_in[6];
  const float* Wo   = (const float*)d_in[7];
  const float* qw   = (const float*)d_in[8];
  const float* kw   = (const float*)d_in[9];

  char* ws = (char*)d_ws;
  bf16* xb   = (bf16*)(ws);                       //  8 MB
  bf16* Wqb  = (bf16*)(ws + ( 8u << 20));         // 16 MB
  bf16* Wkb  = (bf16*)(ws + (24u << 20));         //  2 MB
  bf16* Wvb  = (bf16*)(ws + (26u << 20));         //  2 MB
  bf16* Wob  = (bf16*)(ws + (28u << 20));         //  8 MB
  bf16* qg   = (bf16*)(ws + (36u << 20));         // 16 MB (gate halves only)
  bf16* vt   = (bf16*)(ws + (54u << 20));         //  2 MB  [channel][s]
  bf16* qrot = (bf16*)(ws + (56u << 20));         //  8 MB  [h][s][d] (pre-scaled)
  bf16* krot = (bf16*)(ws + (64u << 20));         //  2 MB  [g][s][d]
  bf16* ctxg = (bf16*)(ws + (66u << 20));         //  8 MB
  float* out = (float*)d_out;

  cvt_all<<<dim3(7168), 256, 0, stream>>>(x, Wq, Wk, Wv, xb, Wqb, Wkb, Wvb);

  gemm_qkv<<<dim3(48, 16), 256, 0, stream>>>(xb, Wqb, Wkb, Wvb,
                                             cosb, sinb, qw, kw,
                                             Wo, Wob,
                                             qg, qrot, krot, vt);
  attn<<<dim3(256), 512, 0, stream>>>(qrot, krot, vt, qg, ctxg);
  gemm_out<<<dim3(16, 16), 256, 0, stream>>>(ctxg, Wob, out);
}

// Round 14
// 130.624 us; speedup vs baseline: 1.2073x; 1.2073x over previous
//
#include <hip/hip_runtime.h>

typedef __bf16 bf16;
typedef __bf16 bf16x4 __attribute__((ext_vector_type(4)));
typedef __bf16 bf16x8 __attribute__((ext_vector_type(8)));
typedef float f32x4 __attribute__((ext_vector_type(4)));

#define DEV static __device__ __forceinline__

constexpr int S  = 2048;
constexpr int D  = 2048;
constexpr int H  = 32;
constexpr int G  = 8;
constexpr int HD = 64;
constexpr int NQG = 2 * H * HD;  // 4096
constexpr int LDP = 136;         // padded LDS stride for attn P tile (128+8)

DEV bf16x8 load8(const bf16* p) { return *reinterpret_cast<const bf16x8*>(p); }

DEV f32x4 mfma16(bf16x8 a, bf16x8 b, f32x4 c) {
  return __builtin_amdgcn_mfma_f32_16x16x32_bf16(a, b, c, 0, 0, 0);
}

DEV void gload_lds16(const bf16* g, bf16* l) {
  __builtin_amdgcn_global_load_lds(
      (const __attribute__((address_space(1))) void*)g,
      (__attribute__((address_space(3))) void*)l, 16, 0, 0);
}

// Raw barrier / waitcnt — used ONLY in attn (1 block/CU regime where in-loop
// prefetch is the only overlap). GEMMs use __syncthreads + cross-block
// overlap (m97 structure): explicit dbuf measured -40% (r10), distance-2
// counted-vmcnt measured -60% (r13) — both via LDS-residency collapse.
#define BARRIER() asm volatile("s_barrier" ::: "memory")
#define VMDRAIN() asm volatile("s_waitcnt vmcnt(0)" ::: "memory")

// Stage a [ROWS][64] bf16 tile into LDS with chunk-XOR swizzle (4-wave form).
template <int NISS>  // ROWS = NISS*32 (4 -> 128 rows, 2 -> 64 rows)
DEV void stage_tile(bf16* lds, const bf16* src_row0, size_t ld, int k0, int tid) {
  const int w = tid >> 6, l = tid & 63;
#pragma unroll
  for (int i = 0; i < NISS; ++i) {
    int blk = w * NISS + i;            // 1KB LDS block
    int r = blk * 8 + (l >> 3);
    int c = (l & 7) ^ (r & 7);
    gload_lds16(src_row0 + (size_t)r * ld + k0 + c * 8, lds + blk * 512);
  }
}

// 8-wave form: one issue per wave stages a 64x64 tile (8 x 1KB blocks).
DEV void stage64_8w(bf16* lds, const bf16* src_row0, size_t ld, int k0, int tid) {
  const int w = tid >> 6, l = tid & 63;
  int r = w * 8 + (l >> 3);
  int c = (l & 7) ^ (r & 7);
  gload_lds16(src_row0 + (size_t)r * ld + k0 + c * 8, lds + w * 512);
}

// Read an 8-elem fragment (logical chunk) from a swizzled [*][64] LDS tile.
DEV bf16x8 fragr(const bf16* T, int row, int chunk) {
  return load8(T + row * 64 + (((chunk ^ (row & 7)) << 3)));
}

DEV float fexp2(float x) { return __builtin_amdgcn_exp2f(x); }
DEV float frcp(float x)  { return __builtin_amdgcn_rcpf(x); }

// ---------------------------------------------------------------------------
// f32 -> bf16 conversions for x, Wq, Wk, Wv (Wo rides inside gemm_qkv).
// ---------------------------------------------------------------------------
__global__ __launch_bounds__(256) void cvt_all(
    const float* __restrict__ x,  const float* __restrict__ wq,
    const float* __restrict__ wk, const float* __restrict__ wv,
    bf16* __restrict__ xb,  bf16* __restrict__ wqb, bf16* __restrict__ wkb,
    bf16* __restrict__ wvb)
{
  long c = (long)blockIdx.x * 256 + threadIdx.x;   // 8-elem chunk id
  const float* src; bf16* dst; long off;
  if      (c <  524288) { src = x;  dst = xb;  off = c; }
  else if (c < 1572864) { src = wq; dst = wqb; off = c -  524288; }
  else if (c < 1703936) { src = wk; dst = wkb; off = c - 1572864; }
  else                  { src = wv; dst = wvb; off = c - 1703936; }
  long i = off * 8;
  const float4* p = reinterpret_cast<const float4*>(src + i);
  float4 a = p[0], b = p[1];
  bf16x8 o;
  o[0] = (bf16)a.x; o[1] = (bf16)a.y; o[2] = (bf16)a.z; o[3] = (bf16)a.w;
  o[4] = (bf16)b.x; o[5] = (bf16)b.y; o[6] = (bf16)b.z; o[7] = (bf16)b.w;
  *reinterpret_cast<bf16x8*>(dst + i) = o;
}

// ---------------------------------------------------------------------------
// Fused RMSNorm + RoPE epilogue helper (wave owns one head's 64 channels).
// ---------------------------------------------------------------------------
DEV void rms_rope_store(f32x4 acc[4][4], bf16* __restrict__ dst,
                        const float* __restrict__ w,
                        const float* __restrict__ cosb,
                        const float* __restrict__ sinb,
                        int s0, int ln, int hi, float outscale)
{
  float wgt[4];
#pragma unroll
  for (int ni = 0; ni < 4; ++ni) wgt[ni] = 1.0f + w[ni * 16 + ln];
#pragma unroll
  for (int mi = 0; mi < 4; ++mi)
#pragma unroll
    for (int j = 0; j < 4; ++j) {
      int s = s0 + mi * 16 + hi * 4 + j;
      float v0 = acc[mi][0][j], v1 = acc[mi][1][j];
      float v2 = acc[mi][2][j], v3 = acc[mi][3][j];
      float ss = v0 * v0 + v1 * v1 + v2 * v2 + v3 * v3;
      ss += __shfl_xor(ss, 1);
      ss += __shfl_xor(ss, 2);
      ss += __shfl_xor(ss, 4);
      ss += __shfl_xor(ss, 8);
      float inv = __builtin_amdgcn_rsqf(ss * (1.0f / 64.0f) + 1e-6f);
      float xf[4] = {v0 * inv * wgt[0], v1 * inv * wgt[1],
                     v2 * inv * wgt[2], v3 * inv * wgt[3]};
#pragma unroll
      for (int ni = 0; ni < 4; ++ni) {
        int d = ni * 16 + ln;
        float c  = cosb[s * HD + d];
        float sn = sinb[s * HD + d];
        float rot = (ni < 2) ? -xf[ni + 2] : xf[ni - 2];
        dst[(size_t)s * HD + d] = (bf16)((xf[ni] * c + rot * sn) * outscale);
      }
    }
}

// ---------------------------------------------------------------------------
// Fused QKV projection + RMSNorm + RoPE epilogue (m97 single-buffer
// structure). blockIdx.x 40..47 are ride-along blocks converting Wo f32->bf16
// (overlapped under the GEMM; Wo is only consumed by gemm_out later).
// ---------------------------------------------------------------------------
__global__ __launch_bounds__(256, 3) void gemm_qkv(
    const bf16* __restrict__ X, const bf16* __restrict__ Wq,
    const bf16* __restrict__ Wk, const bf16* __restrict__ Wv,
    const float* __restrict__ cosb, const float* __restrict__ sinb,
    const float* __restrict__ qw, const float* __restrict__ kw,
    const float* __restrict__ wo, bf16* __restrict__ wob,
    bf16* __restrict__ qg, bf16* __restrict__ qrot,
    bf16* __restrict__ krot, bf16* __restrict__ vt)
{
  __shared__ __align__(16) bf16 As[128 * 64];
  __shared__ __align__(16) bf16 Bs[128 * 64];

  const int tid  = threadIdx.x;
  const int nt = blockIdx.x;

  if (nt >= 40) {
    // ride-along Wo conversion: 128 blocks x 256 thr x 16 iters x 8 elems
    long base = (long)((nt - 40) * 16 + blockIdx.y) * 256 + tid;
#pragma unroll
    for (int it = 0; it < 16; ++it) {
      long i = (base + (long)it * 32768) * 8;
      const float4* p = reinterpret_cast<const float4*>(wo + i);
      float4 a = p[0], b = p[1];
      bf16x8 o;
      o[0] = (bf16)a.x; o[1] = (bf16)a.y; o[2] = (bf16)a.z; o[3] = (bf16)a.w;
      o[4] = (bf16)b.x; o[5] = (bf16)b.y; o[6] = (bf16)b.z; o[7] = (bf16)b.w;
      *reinterpret_cast<bf16x8*>(wob + i) = o;
    }
    return;
  }

  const int wave = tid >> 6;
  const int lane = tid & 63;
  const int ln = lane & 15, hi = lane >> 4;
  const int wm = wave >> 1, wn = wave & 1;
  const int m0 = blockIdx.y * 128;

  const bf16* W; int n0;
  if (nt < 32)      { W = Wq; n0 = nt * 128; }
  else if (nt < 36) { W = Wk; n0 = (nt - 32) * 128; }
  else              { W = Wv; n0 = (nt - 36) * 128; }

  const bf16* arow = X + (size_t)m0 * D;
  const bf16* brow = W + (size_t)n0 * D;

  f32x4 acc[4][4] = {};

  for (int k0 = 0; k0 < D; k0 += 64) {
    __syncthreads();
    stage_tile<4>(As, arow, D, k0, tid);
    stage_tile<4>(Bs, brow, D, k0, tid);
    __syncthreads();
#pragma unroll
    for (int kk = 0; kk < 64; kk += 32) {
      bf16x8 a[4], b[4];
#pragma unroll
      for (int mi = 0; mi < 4; ++mi) a[mi] = fragr(As, wm * 64 + mi * 16 + ln, (kk >> 3) + hi);
#pragma unroll
      for (int ni = 0; ni < 4; ++ni) b[ni] = fragr(Bs, wn * 64 + ni * 16 + ln, (kk >> 3) + hi);
#pragma unroll
      for (int mi = 0; mi < 4; ++mi)
#pragma unroll
        for (int ni = 0; ni < 4; ++ni)
          acc[mi][ni] = mfma16(a[mi], b[ni], acc[mi][ni]);
    }
  }

  const int s0 = m0 + wm * 64;
  if (nt < 32) {
    if (wn == 0) {
      rms_rope_store(acc, qrot + (size_t)nt * S * HD, qw, cosb, sinb,
                     s0, ln, hi, 0.18033688011111204f);
    } else {
#pragma unroll
      for (int mi = 0; mi < 4; ++mi)
#pragma unroll
        for (int ni = 0; ni < 4; ++ni)
#pragma unroll
          for (int j = 0; j < 4; ++j) {
            int r = s0 + mi * 16 + hi * 4 + j;
            int c = nt * 128 + 64 + ni * 16 + ln;
            qg[(size_t)r * NQG + c] = (bf16)acc[mi][ni][j];
          }
    }
  } else if (nt < 36) {
    int g8 = (nt - 32) * 2 + wn;
    rms_rope_store(acc, krot + (size_t)g8 * S * HD, kw, cosb, sinb,
                   s0, ln, hi, 1.0f);
  } else {
    int nrel = (nt - 36) * 128;
#pragma unroll
    for (int mi = 0; mi < 4; ++mi)
#pragma unroll
      for (int ni = 0; ni < 4; ++ni)
#pragma unroll
        for (int j = 0; j < 4; ++j) {
          int r = s0 + mi * 16 + hi * 4 + j;                    // s
          int c = nrel + wn * 64 + ni * 16 + ln;                // channel
          vt[(size_t)c * S + r] = (bf16)acc[mi][ni][j];
        }
  }
}

// ---------------------------------------------------------------------------
// Output projection, 128x64 tile, 512 blocks. f32 output.
// ---------------------------------------------------------------------------
__global__ __launch_bounds__(256, 3) void gemm_out(
    const bf16* __restrict__ A, const bf16* __restrict__ W,
    float* __restrict__ C)
{
  __shared__ __align__(16) bf16 As[128 * 64];
  __shared__ __align__(16) bf16 Bs[64 * 64];

  const int tid  = threadIdx.x;
  const int wave = tid >> 6;
  const int lane = tid & 63;
  const int ln = lane & 15, hi = lane >> 4;
  const int m0 = blockIdx.y * 128;
  const int n0 = blockIdx.x * 64;

  const bf16* arow = A + (size_t)m0 * D;
  const bf16* brow = W + (size_t)n0 * D;

  f32x4 acc[2][4] = {};

  for (int k0 = 0; k0 < D; k0 += 64) {
    __syncthreads();
    stage_tile<4>(As, arow, D, k0, tid);
    stage_tile<2>(Bs, brow, D, k0, tid);
    __syncthreads();
#pragma unroll
    for (int kk = 0; kk < 64; kk += 32) {
      bf16x8 a[2], b[4];
#pragma unroll
      for (int mi = 0; mi < 2; ++mi) a[mi] = fragr(As, wave * 32 + mi * 16 + ln, (kk >> 3) + hi);
#pragma unroll
      for (int ni = 0; ni < 4; ++ni) b[ni] = fragr(Bs, ni * 16 + ln, (kk >> 3) + hi);
#pragma unroll
      for (int mi = 0; mi < 2; ++mi)
#pragma unroll
        for (int ni = 0; ni < 4; ++ni)
          acc[mi][ni] = mfma16(a[mi], b[ni], acc[mi][ni]);
    }
  }

#pragma unroll
  for (int mi = 0; mi < 2; ++mi)
#pragma unroll
    for (int ni = 0; ni < 4; ++ni)
#pragma unroll
      for (int j = 0; j < 4; ++j) {
        int r = m0 + wave * 32 + mi * 16 + hi * 4 + j;
        int c = n0 + ni * 16 + ln;
        C[(size_t)r * D + c] = acc[mi][ni][j];
      }
}

// ---------------------------------------------------------------------------
// Flash attention: swapped QK^T, 8 waves/block (2 heads share K/V staging),
// KVBLK=128 (two 64x64 sub-tiles per barrier round — uniform 17 rounds per
// block), raw-barrier double-buffered prefetch.
// ---------------------------------------------------------------------------
DEV void attn_phase(const bf16* __restrict__ qrot, const bf16* __restrict__ krow,
                    const bf16* __restrict__ vrow, const bf16* __restrict__ qg,
                    bf16* __restrict__ ctxg,
                    bf16* Kbase, bf16* Vbase, bf16* pw,
                    int h, int qchunk, int ln, int hi, int tid)
{
  const int nt = (qchunk >> 1) + 1;   // 128-key rounds; last may be part-masked
  const int qb = qchunk * 64 + ((tid >> 6) & 3) * 16;
  const int q  = qb + ln;

  const bf16* qbase = qrot + ((size_t)h * S + qb + ln) * HD + hi * 8;
  bf16x8 q0 = load8(qbase);
  bf16x8 q1 = load8(qbase + 32);

  f32x4 po[4] = {};
  float m = -INFINITY, l = 0.f;

  stage64_8w(Kbase,        krow,            64, 0,  tid);
  stage64_8w(Kbase + 4096, krow + 64 * 64,  64, 0,  tid);
  stage64_8w(Vbase,        vrow,            S,  0,  tid);
  stage64_8w(Vbase + 4096, vrow,            S,  64, tid);
  VMDRAIN();
  BARRIER();

  int cur = 0;
  for (int t = 0; t < nt; ++t) {
    const bf16* Kc = Kbase + cur * 8192;
    const bf16* Vc = Vbase + cur * 8192;

    if (t + 1 < nt) {
      bf16* Kn = Kbase + (cur ^ 1) * 8192;
      bf16* Vn = Vbase + (cur ^ 1) * 8192;
      stage64_8w(Kn,        krow + (size_t)(t + 1) * 128 * 64,        64, 0, tid);
      stage64_8w(Kn + 4096, krow + ((size_t)(t + 1) * 128 + 64) * 64, 64, 0, tid);
      stage64_8w(Vn,        vrow, S, (t + 1) * 128,      tid);
      stage64_8w(Vn + 4096, vrow, S, (t + 1) * 128 + 64, tid);
    }

    f32x4 sc[2][4];
#pragma unroll
    for (int s = 0; s < 2; ++s) {
      const bf16* Ks = Kc + s * 4096;
      bf16x8 kf0[4], kf1[4];
#pragma unroll
      for (int kr = 0; kr < 4; ++kr) {
        kf0[kr] = fragr(Ks, kr * 16 + ln, hi);
        kf1[kr] = fragr(Ks, kr * 16 + ln, hi + 4);
      }
      __builtin_amdgcn_s_setprio(1);
#pragma unroll
      for (int kr = 0; kr < 4; ++kr) {
        f32x4 z = {};
        z = mfma16(kf0[kr], q0, z);
        sc[s][kr] = mfma16(kf1[kr], q1, z);
      }
      __builtin_amdgcn_s_setprio(0);
    }

    float pmax = -INFINITY;
    if (t == nt - 1) {
      const int key0 = t * 128;
#pragma unroll
      for (int s = 0; s < 2; ++s)
#pragma unroll
        for (int kr = 0; kr < 4; ++kr)
#pragma unroll
          for (int j = 0; j < 4; ++j) {
            int key = key0 + s * 64 + kr * 16 + hi * 4 + j;
            float v = (key <= q) ? sc[s][kr][j] : -INFINITY;
            sc[s][kr][j] = v;
            pmax = fmaxf(pmax, v);
          }
    } else {
#pragma unroll
      for (int s = 0; s < 2; ++s)
#pragma unroll
        for (int kr = 0; kr < 4; ++kr)
#pragma unroll
          for (int j = 0; j < 4; ++j) pmax = fmaxf(pmax, sc[s][kr][j]);
    }
    pmax = fmaxf(pmax, __shfl_xor(pmax, 16));
    pmax = fmaxf(pmax, __shfl_xor(pmax, 32));

    if (__any(pmax > m + 8.0f)) {
      float mn = fmaxf(m, pmax);
      float c  = fexp2(m - mn);
      l *= c;
      float cc[4];
#pragma unroll
      for (int j = 0; j < 4; ++j) cc[j] = __shfl(c, hi * 4 + j);
#pragma unroll
      for (int dt = 0; dt < 4; ++dt)
#pragma unroll
        for (int j = 0; j < 4; ++j) po[dt][j] *= cc[j];
      m = mn;
    }

    float ps = 0.f;
#pragma unroll
    for (int s = 0; s < 2; ++s)
#pragma unroll
      for (int kr = 0; kr < 4; ++kr)
#pragma unroll
        for (int j = 0; j < 4; ++j) {
          float e = fexp2(sc[s][kr][j] - m);
          sc[s][kr][j] = e;
          ps += e;
        }
    ps += __shfl_xor(ps, 16);
    ps += __shfl_xor(ps, 32);
    l += ps;

#pragma unroll
    for (int s = 0; s < 2; ++s)
#pragma unroll
      for (int kr = 0; kr < 4; ++kr) {
        unsigned w0, w1;
        asm("v_cvt_pk_bf16_f32 %0, %1, %2" : "=v"(w0) : "v"(sc[s][kr][0]), "v"(sc[s][kr][1]));
        asm("v_cvt_pk_bf16_f32 %0, %1, %2" : "=v"(w1) : "v"(sc[s][kr][2]), "v"(sc[s][kr][3]));
        uint2 w = {w0, w1};
        *reinterpret_cast<uint2*>(pw + ln * LDP + s * 64 + kr * 16 + hi * 4) = w;
      }
    bf16x8 pa[4];
#pragma unroll
    for (int sl = 0; sl < 4; ++sl) pa[sl] = load8(pw + ln * LDP + sl * 32 + hi * 8);

    __builtin_amdgcn_s_setprio(1);
#pragma unroll
    for (int sl = 0; sl < 4; ++sl) {
      const bf16* Vs = Vc + (sl >> 1) * 4096;
      const int ch = (sl & 1) * 4 + hi;
#pragma unroll
      for (int dt = 0; dt < 4; ++dt)
        po[dt] = mfma16(pa[sl], fragr(Vs, dt * 16 + ln, ch), po[dt]);
    }
    __builtin_amdgcn_s_setprio(0);

    VMDRAIN();   // next round's loads had the whole compute to land
    BARRIER();   // all waves done with buf[cur]; buf[cur^1] ready
    cur ^= 1;
  }

  float lf[4];
#pragma unroll
  for (int j = 0; j < 4; ++j) lf[j] = __shfl(l, hi * 4 + j);
#pragma unroll
  for (int dt = 0; dt < 4; ++dt)
#pragma unroll
    for (int j = 0; j < 4; ++j) {
      int qq = qb + hi * 4 + j;
      int d  = dt * 16 + ln;
      float o  = po[dt][j] * frcp(lf[j]);
      float gv = (float)qg[(size_t)qq * NQG + h * 128 + 64 + d];
      float sg = frcp(1.0f + fexp2(gv * -1.442695040888963f));
      ctxg[(size_t)qq * D + h * 64 + d] = (bf16)(o * sg);
    }
}

__global__ __launch_bounds__(512) void attn(
    const bf16* __restrict__ qrot, const bf16* __restrict__ krot,
    const bf16* __restrict__ vt, const bf16* __restrict__ qg,
    bf16* __restrict__ ctxg)
{
  __shared__ __align__(16) bf16 Kbuf[2][2][64 * 64];   // [dbuf][sub]
  __shared__ __align__(16) bf16 Vbuf[2][2][64 * 64];
  __shared__ __align__(16) bf16 Pl[8][16 * LDP];

  const int tid  = threadIdx.x;
  const int lane = tid & 63;
  const int ln = lane & 15, hi = lane >> 4;

  const int bid = blockIdx.x;
  const int g   = bid & 7;             // XCD-aware: bid%8 shares KV group
  const int i   = bid >> 3;            // 0..31
  const int hp  = i & 1;
  const int pr  = i >> 1;              // 0..15
  const int h   = g * 4 + hp * 2 + ((tid >> 6) >> 2);  // per-wave head
  bf16* pw = &Pl[tid >> 6][0];

  const bf16* krow = krot + (size_t)g * S * HD;   // [key][d], ld=64
  const bf16* vrow = vt + (size_t)g * 64 * S;     // [channel][s], ld=S

  attn_phase(qrot, krow, vrow, qg, ctxg,
             &Kbuf[0][0][0], &Vbuf[0][0][0], pw, h, pr, ln, hi, tid);
  attn_phase(qrot, krow, vrow, qg, ctxg,
             &Kbuf[0][0][0], &Vbuf[0][0][0], pw, h, 31 - pr, ln, hi, tid);
}

// ---------------------------------------------------------------------------
extern "C" void kernel_launch(void* const* d_in, const int* in_sizes, int n_in,
                              void* d_out, int out_size, void* d_ws, size_t ws_size,
                              hipStream_t stream) {
  const float* x    = (const float*)d_in[0];
  const float* cosb = (const float*)d_in[2];
  const float* sinb = (const float*)d_in[3];
  const float* Wq   = (const float*)d_in[4];
  const float* Wk   = (const float*)d_in[5];
  const float* Wv   = (const float*)d_in[6];
  const float* Wo   = (const float*)d_in[7];
  const float* qw   = (const float*)d_in[8];
  const float* kw   = (const float*)d_in[9];

  char* ws = (char*)d_ws;
  bf16* xb   = (bf16*)(ws);                       //  8 MB
  bf16* Wqb  = (bf16*)(ws + ( 8u << 20));         // 16 MB
  bf16* Wkb  = (bf16*)(ws + (24u << 20));         //  2 MB
  bf16* Wvb  = (bf16*)(ws + (26u << 20));         //  2 MB
  bf16* Wob  = (bf16*)(ws + (28u << 20));         //  8 MB
  bf16* qg   = (bf16*)(ws + (36u << 20));         // 16 MB (gate halves only)
  bf16* vt   = (bf16*)(ws + (54u << 20));         //  2 MB  [channel][s]
  bf16* qrot = (bf16*)(ws + (56u << 20));         //  8 MB  [h][s][d] (pre-scaled)
  bf16* krot = (bf16*)(ws + (64u << 20));         //  2 MB  [g][s][d]
  bf16* ctxg = (bf16*)(ws + (66u << 20));         //  8 MB
  float* out = (float*)d_out;

  cvt_all<<<dim3(7168), 256, 0, stream>>>(x, Wq, Wk, Wv, xb, Wqb, Wkb, Wvb);

  gemm_qkv<<<dim3(48, 16), 256, 0, stream>>>(xb, Wqb, Wkb, Wvb,
                                             cosb, sinb, qw, kw,
                                             Wo, Wob,
                                             qg, qrot, krot, vt);
  attn<<<dim3(256), 512, 0, stream>>>(qrot, krot, vt, qg, ctxg);
  gemm_out<<<dim3(32, 16), 256, 0, stream>>>(ctxg, Wob, out);
}